// Round 6
// baseline (7133.130 us; speedup 1.0000x reference)
//
#include <hip/hip_runtime.h>
#include <hip/hip_bf16.h>

// out[b,o,hw] = sum_c W[o,c] * relu(x[b,c,hw]*scale[c] + shift[c])
// B=256, Cin=2112, Cout=192, HW=49, all fp32 in HBM. bf16 MFMA internally.
//
// R6: three streaming kernels, each a measured-good access pattern.
//  1) w_repack: W fp32 -> bf16 A-fragment order (811 KB, L2-resident).
//  2) bnpack:   x fp32 -> BN+ReLU -> bf16, transposed to B-fragment order
//     via double-buffered LDS tile (flat dwordx4 reads -- the ONLY aligned
//     vector read of x since row stride 196 B is not 16B-aligned).
//     hpack[(b*66+ks)*49+hw][c'] lives in workspace (53 MB, L3-resident).
//  3) gemm:     both operands contiguous dwordx4 per lane, barrier-free,
//     disjoint direct stores (no atomics/memset).

#define CIN    2112
#define COUT   192
#define HWS    49
#define BK     32
#define NSTEP  (CIN / BK)     // 66
#define EPSV   1e-5f
#define SLAB   (BK * HWS)     // 1568 elements per (b,ks) tile

typedef __bf16 bf16;
typedef __attribute__((ext_vector_type(8))) __bf16 bf16x8;
typedef __attribute__((ext_vector_type(4))) float  f32x4;

// ---------- kernel 1: W fp32 -> bf16 in A-fragment order ----------
// Wb[((ks*12 + gmt)*64 + lane)*8 + j] = W[(gmt*16+(lane&15))*CIN + ks*32+(lane>>4)*8+j]
__global__ __launch_bounds__(256)
void w_repack_kernel(const float* __restrict__ W, bf16* __restrict__ Wb) {
    const int t = blockIdx.x * 256 + threadIdx.x;       // 66*12*64 = 50688
    if (t >= NSTEP * 12 * 64) return;
    const int lane = t & 63;
    const int gmt  = (t >> 6) % 12;
    const int ks   = t / (12 * 64);
    const int row  = gmt * 16 + (lane & 15);
    const int k    = ks * BK + (lane >> 4) * 8;
    const float* src = W + (size_t)row * CIN + k;
    f32x4 a = *(const f32x4*)src;
    f32x4 b = *(const f32x4*)(src + 4);
    bf16x8 o;
    #pragma unroll
    for (int j = 0; j < 4; j++) { o[j] = (bf16)a[j]; o[j + 4] = (bf16)b[j]; }
    *(bf16x8*)(Wb + (size_t)t * 8) = o;
}

// ---------- kernel 2: x -> BN+ReLU -> bf16 transposed pack ----------
// Tile T = b*66+ks: reads x flat slab [T*1568, T*1568+1568), writes
// hpack[T*1568 + hw*32 + c'] (c' = channel within step). 8 tiles/block.
__global__ __launch_bounds__(256)
void bnpack_kernel(const float* __restrict__ x,
                   const float* __restrict__ gamma,
                   const float* __restrict__ beta,
                   const float* __restrict__ rmean,
                   const float* __restrict__ rvar,
                   bf16* __restrict__ hpack)
{
    __shared__ float2 ss[CIN + 2];
    __shared__ __align__(16) bf16 bt[2][SLAB];

    const int tid = threadIdx.x;

    // BN table (amortized over 8 tiles)
    for (int c = tid; c < CIN; c += 256) {
        float inv = rsqrtf(rvar[c] + EPSV);
        float s   = gamma[c] * inv;
        ss[c] = make_float2(s, beta[c] - rmean[c] * s);
    }
    if (tid < 2) ss[CIN + tid] = make_float2(0.f, 0.f);

    // tile-local geometry (identical for every tile)
    const bool act = tid < 196;
    const int fb   = tid * 8;
    const int cl0  = fb / 49;
    const int hw0  = fb - cl0 * 49;
    int jwTh = 8;                          // first j that wraps channels
    if (hw0 + 8 > HWS) jwTh = HWS - hw0;   // last thread never wraps
    int addrs[8];
    #pragma unroll
    for (int j = 0; j < 8; j++) {
        int hw = hw0 + j, cl = cl0;
        if (hw >= HWS) { hw -= HWS; cl += 1; }
        const int rot = ((cl >> 3) + (hw >> 2)) & 3;   // bank swizzle
        addrs[j] = hw * BK + rot * 8 + (cl & 7);
    }
    // reader geometry: output group o = tid*8 -> (ohw, ocg)
    const int ohw   = tid >> 2;
    const int ocg   = tid & 3;
    const int ldsrd = ohw * BK + (((ocg) + (ohw >> 2)) & 3) * 8;

    const int T0 = blockIdx.x * 8;
    const float* xs = x + (size_t)T0 * SLAB + fb;

    f32x4 xv0, xv1;
    if (act) { xv0 = *(const f32x4*)xs; xv1 = *(const f32x4*)(xs + 4); }

    __syncthreads();   // ss ready

    int p = 0;
    for (int t = 0; t < 8; t++) {
        const int T     = T0 + t;
        const int cbase = (T % NSTEP) * BK;   // ks*32

        if (act) {
            const float2 s0 = ss[cbase + cl0];
            const float2 s1 = ss[cbase + cl0 + 1];
            #pragma unroll
            for (int j = 0; j < 8; j++) {
                const float xj = (j < 4) ? xv0[j] : xv1[j - 4];
                const float sc = (j >= jwTh) ? s1.x : s0.x;
                const float sh = (j >= jwTh) ? s1.y : s0.y;
                bt[p][addrs[j]] = (bf16)fmaxf(fmaf(xj, sc, sh), 0.f);
            }
        }
        __syncthreads();   // bt[p] visible; prior reads of bt[p^1] done

        // prefetch next tile while this tile's LDS read + store proceed
        if (t < 7 && act) {
            xs += SLAB;
            xv0 = *(const f32x4*)xs;
            xv1 = *(const f32x4*)(xs + 4);
        }
        if (act) {
            bf16x8 o = *(const bf16x8*)&bt[p][ldsrd];
            *(bf16x8*)(hpack + (size_t)T * SLAB + fb) = o;
        }
        p ^= 1;
    }
}

// ---------- kernel 3: GEMM, barrier-free, all-coalesced ----------
// grid 1024 = (b, Cout-quarter). Wave wv = n-tile (hw window 16*wv),
// 3 m-tiles/wave. Per step: 3 A-frag + 1 B-frag dwordx4 loads, 3 MFMA.
__global__ __launch_bounds__(256, 4)
void gemm_kernel(const bf16* __restrict__ hpack,
                 const bf16* __restrict__ Wb,
                 float* __restrict__ out)
{
    const int tid  = threadIdx.x;
    const int bid  = blockIdx.x;
    const int b    = bid >> 2;
    const int qt   = bid & 3;            // Cout quarter: rows qt*48..
    const int gmt0 = qt * 3;             // first global m-tile

    const int lane = tid & 63;
    const int wv   = tid >> 6;
    const int l15  = lane & 15;
    const int q    = lane >> 4;

    int hwL = wv * 16 + l15;
    if (hwL > 48) hwL = 48;              // wave 3 lanes 1..15 duplicate col 48

    const bf16* bp = hpack + (size_t)b * (NSTEP * SLAB) + hwL * BK + q * 8;
    const bf16* ap = Wb + (((size_t)gmt0) * 64 + lane) * 8;

    f32x4 acc[3];
    #pragma unroll
    for (int i = 0; i < 3; i++) acc[i] = (f32x4)(0.f);

    // depth-2 rings (compiler may sink; loads are fat either way)
    bf16x8 br[2], ar[2][3];
    #pragma unroll
    for (int d = 0; d < 2; d++) {
        br[d] = *(const bf16x8*)(bp + (size_t)d * SLAB);
        #pragma unroll
        for (int mt = 0; mt < 3; mt++)
            ar[d][mt] = *(const bf16x8*)(ap + ((size_t)d * 12 + mt) * (64 * 8));
    }

    for (int ks = 0; ks < NSTEP; ks++) {
        const int s2 = ks & 1;
        const bf16x8 bfrag = br[s2];
        #pragma unroll
        for (int mt = 0; mt < 3; mt++)
            acc[mt] = __builtin_amdgcn_mfma_f32_16x16x32_bf16(ar[s2][mt], bfrag, acc[mt], 0, 0, 0);

        int kf = ks + 2; if (kf > NSTEP - 1) kf = NSTEP - 1;
        br[s2] = *(const bf16x8*)(bp + (size_t)kf * SLAB);
        #pragma unroll
        for (int mt = 0; mt < 3; mt++)
            ar[s2][mt] = *(const bf16x8*)(ap + ((size_t)kf * 12 + mt) * (64 * 8));
    }

    // epilogue: col=lane&15 -> hw = 16*wv+l15, row=q*4+r. Disjoint stores.
    const int hw = wv * 16 + l15;
    if (hw < HWS) {
        #pragma unroll
        for (int mt = 0; mt < 3; mt++) {
            #pragma unroll
            for (int r = 0; r < 4; r++) {
                const int row = qt * 48 + mt * 16 + q * 4 + r;
                out[((size_t)b * COUT + row) * HWS + hw] = acc[mt][r];
            }
        }
    }
}

// ---------- fallback (R4 fused kernel) if workspace too small ----------
__global__ __launch_bounds__(256, 2)
void fused_fallback_kernel(const float* __restrict__ x,
                           const float* __restrict__ gamma,
                           const float* __restrict__ beta,
                           const float* __restrict__ rmean,
                           const float* __restrict__ rvar,
                           const bf16*  __restrict__ Wb,
                           float* __restrict__ out)
{
    __shared__ __align__(16) float ssf[2 * CIN];
    const int tid  = threadIdx.x;
    const int b    = blockIdx.x >> 1;
    const int half = blockIdx.x & 1;
    const int gmt0 = half * 6;
    for (int c = tid; c < CIN; c += 256) {
        float inv = rsqrtf(rvar[c] + EPSV);
        float s   = gamma[c] * inv;
        ssf[2 * c] = s; ssf[2 * c + 1] = beta[c] - rmean[c] * s;
    }
    const int lane = tid & 63, wv = tid >> 6, l15 = lane & 15, q = lane >> 4;
    const int hw0 = wv * 11;
    const float* xL = x + (size_t)b * (CIN * HWS) + (q * 8) * HWS + hw0 + l15;
    const bf16* wbL = Wb + ((size_t)gmt0 * 64 + lane) * 8;
    const float* ssq = ssf + q * 16;
    f32x4 acc[6];
    #pragma unroll
    for (int i = 0; i < 6; i++) acc[i] = (f32x4)(0.f);
    __syncthreads();
    for (int ks = 0; ks < NSTEP; ks++) {
        const float* sb = ssq + ks * 64;
        bf16x8 bfrag;
        #pragma unroll
        for (int j = 0; j < 8; j++) {
            float sc = sb[2 * j], sh = sb[2 * j + 1];
            float xv = xL[(ks * BK + j) * HWS - (q * 8) * HWS + (q * 8) * HWS];
            // simple per-element load (fallback path, correctness only)
            xv = x[(size_t)b * (CIN * HWS) + (size_t)(ks * BK + q * 8 + j) * HWS + hw0 + l15];
            bfrag[j] = (bf16)fmaxf(fmaf(xv, sc, sh), 0.f);
        }
        const bf16* p = wbL + (size_t)ks * (12 * 64 * 8);
        #pragma unroll
        for (int mt = 0; mt < 6; mt++)
            acc[mt] = __builtin_amdgcn_mfma_f32_16x16x32_bf16(
                *(const bf16x8*)(p + mt * (64 * 8)), bfrag, acc[mt], 0, 0, 0);
    }
    const int hw = hw0 + l15;
    const int mbase = half * 96;
    const bool writer = (wv == 3) || (l15 < 11);
    if (writer) {
        #pragma unroll
        for (int mt = 0; mt < 6; mt++)
            #pragma unroll
            for (int r = 0; r < 4; r++)
                out[((size_t)b * COUT + mbase + mt * 16 + q * 4 + r) * HWS + hw] = acc[mt][r];
    }
}

extern "C" void kernel_launch(void* const* d_in, const int* in_sizes, int n_in,
                              void* d_out, int out_size, void* d_ws, size_t ws_size,
                              hipStream_t stream) {
    const float* x     = (const float*)d_in[0];
    const float* gamma = (const float*)d_in[1];
    const float* beta  = (const float*)d_in[2];
    const float* rmean = (const float*)d_in[3];
    const float* rvar  = (const float*)d_in[4];
    const float* W     = (const float*)d_in[5];
    float* out = (float*)d_out;

    bf16* Wb = (bf16*)d_ws;                                   // 811,008 B
    const size_t hoff   = 1048576;                            // 1 MB align
    const size_t hbytes = (size_t)256 * NSTEP * SLAB * 2;     // 52,987,904 B
    bf16* hpack = (bf16*)((char*)d_ws + hoff);

    w_repack_kernel<<<dim3(198), dim3(256), 0, stream>>>(W, Wb);

    if (ws_size >= hoff + hbytes) {
        bnpack_kernel<<<dim3(2112), dim3(256), 0, stream>>>(
            x, gamma, beta, rmean, rvar, hpack);
        gemm_kernel<<<dim3(1024), dim3(256), 0, stream>>>(hpack, Wb, out);
    } else {
        fused_fallback_kernel<<<dim3(512), dim3(256), 0, stream>>>(
            x, gamma, beta, rmean, rvar, Wb, out);
    }
}

// Round 7
// 221.886 us; speedup vs baseline: 32.1477x; 32.1477x over previous
//
#include <hip/hip_runtime.h>
#include <hip/hip_bf16.h>

// out[b,o,hw] = sum_c W[o,c] * relu(x[b,c,hw]*scale[c] + shift[c])
// B=256, Cin=2112, Cout=192, HW=49, all fp32 in HBM. bf16 MFMA internally.
//
// R7 = R6 with the gemm K-loop FULLY UNROLLED. R6's rolled loop made
// br[s2]/ar[s2][mt] dynamically-indexed private arrays -> scratch spill
// (2 GB WRITE_SIZE, 6984 us). Static indices keep the rings in VGPRs.
//
//  1) w_repack: W fp32 -> bf16 A-fragment order (811 KB, L2-resident).
//  2) bnpack:   x fp32 -> BN+ReLU -> bf16, transposed to B-fragment order
//     via double-buffered LDS tile (flat dwordx4 reads; row stride 196 B
//     is not 16B-aligned so the flat slab is the only aligned vector read).
//  3) gemm:     both operands contiguous dwordx4 per lane, barrier-free,
//     fully unrolled, disjoint direct stores.

#define CIN    2112
#define COUT   192
#define HWS    49
#define BK     32
#define NSTEP  (CIN / BK)     // 66
#define EPSV   1e-5f
#define SLAB   (BK * HWS)     // 1568 elements per (b,ks) tile

typedef __bf16 bf16;
typedef __attribute__((ext_vector_type(8))) __bf16 bf16x8;
typedef __attribute__((ext_vector_type(4))) float  f32x4;

// ---------- kernel 1: W fp32 -> bf16 in A-fragment order ----------
__global__ __launch_bounds__(256)
void w_repack_kernel(const float* __restrict__ W, bf16* __restrict__ Wb) {
    const int t = blockIdx.x * 256 + threadIdx.x;       // 66*12*64 = 50688
    if (t >= NSTEP * 12 * 64) return;
    const int lane = t & 63;
    const int gmt  = (t >> 6) % 12;
    const int ks   = t / (12 * 64);
    const int row  = gmt * 16 + (lane & 15);
    const int k    = ks * BK + (lane >> 4) * 8;
    const float* src = W + (size_t)row * CIN + k;
    f32x4 a = *(const f32x4*)src;
    f32x4 b = *(const f32x4*)(src + 4);
    bf16x8 o;
    #pragma unroll
    for (int j = 0; j < 4; j++) { o[j] = (bf16)a[j]; o[j + 4] = (bf16)b[j]; }
    *(bf16x8*)(Wb + (size_t)t * 8) = o;
}

// ---------- kernel 2: x -> BN+ReLU -> bf16 transposed pack ----------
__global__ __launch_bounds__(256)
void bnpack_kernel(const float* __restrict__ x,
                   const float* __restrict__ gamma,
                   const float* __restrict__ beta,
                   const float* __restrict__ rmean,
                   const float* __restrict__ rvar,
                   bf16* __restrict__ hpack)
{
    __shared__ float2 ss[CIN + 2];
    __shared__ __align__(16) bf16 bt[2][SLAB];

    const int tid = threadIdx.x;

    for (int c = tid; c < CIN; c += 256) {
        float inv = rsqrtf(rvar[c] + EPSV);
        float s   = gamma[c] * inv;
        ss[c] = make_float2(s, beta[c] - rmean[c] * s);
    }
    if (tid < 2) ss[CIN + tid] = make_float2(0.f, 0.f);

    const bool act = tid < 196;
    const int fb   = tid * 8;
    const int cl0  = fb / 49;
    const int hw0  = fb - cl0 * 49;
    int jwTh = 8;
    if (hw0 + 8 > HWS) jwTh = HWS - hw0;
    int addrs[8];
    #pragma unroll
    for (int j = 0; j < 8; j++) {
        int hw = hw0 + j, cl = cl0;
        if (hw >= HWS) { hw -= HWS; cl += 1; }
        const int rot = ((cl >> 3) + (hw >> 2)) & 3;   // bank swizzle
        addrs[j] = hw * BK + rot * 8 + (cl & 7);
    }
    const int ohw   = tid >> 2;
    const int ocg   = tid & 3;
    const int ldsrd = ohw * BK + ((ocg + (ohw >> 2)) & 3) * 8;

    const int T0 = blockIdx.x * 8;
    const float* xs = x + (size_t)T0 * SLAB + fb;

    f32x4 xv0, xv1;
    if (act) { xv0 = *(const f32x4*)xs; xv1 = *(const f32x4*)(xs + 4); }

    __syncthreads();   // ss ready

    int p = 0;
    #pragma unroll
    for (int t = 0; t < 8; t++) {
        const int T     = T0 + t;
        const int cbase = (T % NSTEP) * BK;

        if (act) {
            const float2 s0 = ss[cbase + cl0];
            const float2 s1 = ss[cbase + cl0 + 1];
            #pragma unroll
            for (int j = 0; j < 8; j++) {
                const float xj = (j < 4) ? xv0[j] : xv1[j - 4];
                const float sc = (j >= jwTh) ? s1.x : s0.x;
                const float sh = (j >= jwTh) ? s1.y : s0.y;
                bt[p][addrs[j]] = (bf16)fmaxf(fmaf(xj, sc, sh), 0.f);
            }
        }
        __syncthreads();

        if (t < 7 && act) {
            xs += SLAB;
            xv0 = *(const f32x4*)xs;
            xv1 = *(const f32x4*)(xs + 4);
        }
        if (act) {
            bf16x8 o = *(const bf16x8*)&bt[p][ldsrd];
            *(bf16x8*)(hpack + (size_t)T * SLAB + fb) = o;
        }
        p ^= 1;
    }
}

// ---------- kernel 3: GEMM, barrier-free, fully unrolled ----------
__global__ __launch_bounds__(256, 4)
void gemm_kernel(const bf16* __restrict__ hpack,
                 const bf16* __restrict__ Wb,
                 float* __restrict__ out)
{
    const int tid  = threadIdx.x;
    const int bid  = blockIdx.x;
    const int b    = bid >> 2;
    const int qt   = bid & 3;            // Cout quarter: rows qt*48..
    const int gmt0 = qt * 3;

    const int lane = tid & 63;
    const int wv   = tid >> 6;
    const int l15  = lane & 15;
    const int q    = lane >> 4;

    int hwL = wv * 16 + l15;
    if (hwL > 48) hwL = 48;              // wave 3 lanes 1..15 duplicate col 48

    const bf16* bp = hpack + (size_t)b * (NSTEP * SLAB) + hwL * BK + q * 8;
    const bf16* ap = Wb + ((size_t)gmt0 * 64 + lane) * 8;

    f32x4 acc[3];
    #pragma unroll
    for (int i = 0; i < 3; i++) acc[i] = (f32x4)(0.f);

    bf16x8 br[2], ar[2][3];
    #pragma unroll
    for (int d = 0; d < 2; d++) {
        br[d] = *(const bf16x8*)(bp + (size_t)d * SLAB);
        #pragma unroll
        for (int mt = 0; mt < 3; mt++)
            ar[d][mt] = *(const bf16x8*)(ap + ((size_t)d * 12 + mt) * (64 * 8));
    }

    #pragma unroll   // FULL unroll: all ring indices become compile-time
    for (int ks = 0; ks < NSTEP; ks++) {
        const int s2 = ks & 1;
        const bf16x8 bfrag = br[s2];
        #pragma unroll
        for (int mt = 0; mt < 3; mt++)
            acc[mt] = __builtin_amdgcn_mfma_f32_16x16x32_bf16(ar[s2][mt], bfrag, acc[mt], 0, 0, 0);

        int kf = ks + 2; if (kf > NSTEP - 1) kf = NSTEP - 1;
        br[s2] = *(const bf16x8*)(bp + (size_t)kf * SLAB);
        #pragma unroll
        for (int mt = 0; mt < 3; mt++)
            ar[s2][mt] = *(const bf16x8*)(ap + ((size_t)kf * 12 + mt) * (64 * 8));
    }

    // epilogue: col=lane&15 -> hw = 16*wv+l15, row=q*4+r. Disjoint stores.
    const int hw = wv * 16 + l15;
    if (hw < HWS) {
        #pragma unroll
        for (int mt = 0; mt < 3; mt++) {
            #pragma unroll
            for (int r = 0; r < 4; r++) {
                const int row = qt * 48 + mt * 16 + q * 4 + r;
                out[((size_t)b * COUT + row) * HWS + hw] = acc[mt][r];
            }
        }
    }
}

// ---------- fallback (only if workspace too small; not expected) ----------
__global__ __launch_bounds__(256, 2)
void fused_fallback_kernel(const float* __restrict__ x,
                           const float* __restrict__ gamma,
                           const float* __restrict__ beta,
                           const float* __restrict__ rmean,
                           const float* __restrict__ rvar,
                           const bf16*  __restrict__ Wb,
                           float* __restrict__ out)
{
    __shared__ __align__(16) float ssf[2 * CIN];
    const int tid  = threadIdx.x;
    const int b    = blockIdx.x >> 1;
    const int half = blockIdx.x & 1;
    const int gmt0 = half * 6;
    for (int c = tid; c < CIN; c += 256) {
        float inv = rsqrtf(rvar[c] + EPSV);
        float s   = gamma[c] * inv;
        ssf[2 * c] = s; ssf[2 * c + 1] = beta[c] - rmean[c] * s;
    }
    const int lane = tid & 63, wv = tid >> 6, l15 = lane & 15, q = lane >> 4;
    const int hw0 = wv * 11;
    const bf16* wbL = Wb + ((size_t)gmt0 * 64 + lane) * 8;
    const float* ssq = ssf + q * 16;
    f32x4 acc[6];
    #pragma unroll
    for (int i = 0; i < 6; i++) acc[i] = (f32x4)(0.f);
    __syncthreads();
    for (int ks = 0; ks < NSTEP; ks++) {
        const float* sb = ssq + ks * 64;
        bf16x8 bfrag;
        #pragma unroll
        for (int j = 0; j < 8; j++) {
            float sc = sb[2 * j], sh = sb[2 * j + 1];
            float xv = x[(size_t)b * (CIN * HWS) + (size_t)(ks * BK + q * 8 + j) * HWS + hw0 + l15];
            bfrag[j] = (bf16)fmaxf(fmaf(xv, sc, sh), 0.f);
        }
        const bf16* p = wbL + (size_t)ks * (12 * 64 * 8);
        #pragma unroll
        for (int mt = 0; mt < 6; mt++)
            acc[mt] = __builtin_amdgcn_mfma_f32_16x16x32_bf16(
                *(const bf16x8*)(p + mt * (64 * 8)), bfrag, acc[mt], 0, 0, 0);
    }
    const int hw = hw0 + l15;
    const int mbase = half * 96;
    const bool writer = (wv == 3) || (l15 < 11);
    if (writer) {
        #pragma unroll
        for (int mt = 0; mt < 6; mt++)
            #pragma unroll
            for (int r = 0; r < 4; r++)
                out[((size_t)b * COUT + mbase + mt * 16 + q * 4 + r) * HWS + hw] = acc[mt][r];
    }
}

extern "C" void kernel_launch(void* const* d_in, const int* in_sizes, int n_in,
                              void* d_out, int out_size, void* d_ws, size_t ws_size,
                              hipStream_t stream) {
    const float* x     = (const float*)d_in[0];
    const float* gamma = (const float*)d_in[1];
    const float* beta  = (const float*)d_in[2];
    const float* rmean = (const float*)d_in[3];
    const float* rvar  = (const float*)d_in[4];
    const float* W     = (const float*)d_in[5];
    float* out = (float*)d_out;

    bf16* Wb = (bf16*)d_ws;                                   // 811,008 B
    const size_t hoff   = 1048576;                            // 1 MB align
    const size_t hbytes = (size_t)256 * NSTEP * SLAB * 2;     // 52,987,904 B
    bf16* hpack = (bf16*)((char*)d_ws + hoff);

    w_repack_kernel<<<dim3(198), dim3(256), 0, stream>>>(W, Wb);

    if (ws_size >= hoff + hbytes) {
        bnpack_kernel<<<dim3(2112), dim3(256), 0, stream>>>(
            x, gamma, beta, rmean, rvar, hpack);
        gemm_kernel<<<dim3(1024), dim3(256), 0, stream>>>(hpack, Wb, out);
    } else {
        fused_fallback_kernel<<<dim3(512), dim3(256), 0, stream>>>(
            x, gamma, beta, rmean, rvar, Wb, out);
    }
}